// Round 13
// baseline (197.972 us; speedup 1.0000x reference)
//
#include <hip/hip_runtime.h>
#include <hip/hip_bf16.h>

#define NB 16
#define NQ 128
#define NK 512
#define DIN 256   // QS == KS == 256
#define NH 128
#define NDV 256

// tanh(x) = 1 - 2/(1+e^{2x}); saturates to +-1 for large |x|, NaN-free for finite x.
__device__ __forceinline__ float fast_tanh(float x) {
    float t = __builtin_amdgcn_exp2f(x * 2.8853900817779268f);
    return 1.0f - 2.0f * __builtin_amdgcn_rcpf(t + 1.0f);
}

// P[b,r,h] = sum_d X[b,r,d] * W[d,h].  X f32 [B,R,256], W f32 [256,128], P f32.
// Block: 256 thr, 16 rows of one b. h = tid&127, rg = tid>>7 -> 8 rows each.
// W read from global (coalesced 512B/wave, L2-resident). X tile in 16KB LDS.
template<int R>
__global__ __launch_bounds__(256) void proj_kernel(
    const float* __restrict__ X,
    const float* __restrict__ W,
    float* __restrict__ P)
{
    __shared__ float Xl[16 * DIN];   // 16KB
    const int tid = threadIdx.x;
    const int tpb = R / 16;
    const int b = blockIdx.x / tpb;
    const int r0 = (blockIdx.x % tpb) * 16;

    const float4* Xg = (const float4*)(X + ((size_t)b * R + r0) * DIN);  // 1024 chunks
    float4* Xls = (float4*)Xl;
    #pragma unroll
    for (int i = 0; i < 4; ++i) Xls[tid + 256 * i] = Xg[tid + 256 * i];
    __syncthreads();

    const int h  = tid & 127;
    const int rg = tid >> 7;           // rows rg*8 .. rg*8+7
    float acc[8];
    #pragma unroll
    for (int r = 0; r < 8; ++r) acc[r] = 0.f;

    #pragma unroll 4
    for (int d = 0; d < DIN; ++d) {
        float w = W[d * NH + h];       // coalesced across lanes
        #pragma unroll
        for (int r = 0; r < 8; ++r)
            acc[r] += Xl[(rg * 8 + r) * DIN + d] * w;   // wave-uniform -> broadcast
    }
    float* Pp = P + ((size_t)b * R + r0) * NH + h;
    #pragma unroll
    for (int r = 0; r < 8; ++r) Pp[(rg * 8 + r) * NH] = acc[r];
}

// Fused scores + masked softmax + attn@V.  Block = (b, 4 q rows), 256 thr = 4 waves.
// Grid = 16 * 32 = 512 blocks (~2 blocks/CU).
// Phase A: per 64-key chunk, stage KP into LDS coalesced (pad 129 -> (k+h)%32
// banks, 2-way = free), thread (row=tid>>6, k=tid&63) accumulates its score.
// Softmax + Phase C are per-wave private (wave w owns row w) -> no barriers.
__global__ __launch_bounds__(256) void attn_fused_kernel(
    const float* __restrict__ QP, const float* __restrict__ KP,
    const float* __restrict__ wv, const int* __restrict__ vlen,
    const float* __restrict__ V, float* __restrict__ OUT)
{
    __shared__ float qpl[4 * NH];        // 2KB
    __shared__ float wvl[NH];            // 0.5KB
    __shared__ float kpl[64 * 129];      // 33KB staged K-proj chunk
    __shared__ float sc[4][NK];          // 8KB scores -> attn
    const int tid = threadIdx.x;
    const int b  = blockIdx.x >> 5;
    const int q0 = (blockIdx.x & 31) * 4;

    const float* qg = QP + ((size_t)b * NQ + q0) * NH;
    for (int i = tid; i < 4 * NH; i += 256) qpl[i] = qg[i];
    if (tid < NH) wvl[tid] = wv[tid];
    __syncthreads();

    int vl = vlen[b];
    vl = vl < 1 ? 1 : (vl > NK ? NK : vl);

    const int row = tid >> 6;            // wave w owns q-row w
    const int kl  = tid & 63;
    const float* qrow = &qpl[row * NH];  // wave-uniform base -> b128 broadcast

    for (int kc = 0; kc < 8; ++kc) {
        // ---- stage 64 k-rows of KP, coalesced float4 global -> padded LDS
        {
            const float4* kg = (const float4*)(KP + ((size_t)b * NK + kc * 64) * NH);
            #pragma unroll
            for (int i = 0; i < 8; ++i) {
                const int idx  = i * 256 + tid;        // 0..2047
                const int krow = idx >> 5, c4 = idx & 31;
                float4 v = kg[(size_t)krow * 32 + c4];
                float* dst = &kpl[krow * 129 + c4 * 4];
                dst[0] = v.x; dst[1] = v.y; dst[2] = v.z; dst[3] = v.w;
            }
        }
        __syncthreads();

        // ---- score for (row, k = kc*64 + kl)
        {
            const float* krow_l = &kpl[kl * 129];
            float a = 0.f;
            #pragma unroll 4
            for (int h = 0; h < NH; h += 4) {
                float4 wq = *(const float4*)&wvl[h];    // broadcast
                float4 qv = *(const float4*)&qrow[h];   // broadcast
                a += wq.x * fast_tanh(qv.x + krow_l[h]);
                a += wq.y * fast_tanh(qv.y + krow_l[h + 1]);
                a += wq.z * fast_tanh(qv.z + krow_l[h + 2]);
                a += wq.w * fast_tanh(qv.w + krow_l[h + 3]);
            }
            const int k = kc * 64 + kl;
            sc[row][k] = (k < vl) ? a : -1e6f;
        }
        __syncthreads();   // kpl reused next chunk
    }

    // ---- masked softmax, wave-private: wave w reads/writes only sc[w][*]
    const int w = row, lane = kl;
    {
        float vals[8];
        float m = -3.0e38f;
        #pragma unroll
        for (int i = 0; i < 8; ++i) { vals[i] = sc[w][lane + 64 * i]; m = fmaxf(m, vals[i]); }
        #pragma unroll
        for (int off = 32; off; off >>= 1) m = fmaxf(m, __shfl_xor(m, off, 64));
        float s = 0.f;
        #pragma unroll
        for (int i = 0; i < 8; ++i) {
            vals[i] = __builtin_amdgcn_exp2f((vals[i] - m) * 1.4426950408889634f);
            s += vals[i];
        }
        #pragma unroll
        for (int off = 32; off; off >>= 1) s += __shfl_xor(s, off, 64);
        const float invs = 1.0f / s;     // s >= 1
        #pragma unroll
        for (int i = 0; i < 8; ++i) sc[w][lane + 64 * i] = vals[i] * invs;
    }

    // ---- out[q0+w, :] = sum_k attn[w][k] * V[b,k,:]; lane owns d = lane*4..+3
    {
        float a0 = 0.f, a1 = 0.f, a2 = 0.f, a3 = 0.f;
        const float* vb = V + (size_t)b * NK * NDV + lane * 4;
        #pragma unroll 4
        for (int k = 0; k < NK; ++k) {
            float4 v4 = *(const float4*)(vb + (size_t)k * NDV);   // 1KB/wave coalesced
            const float p = sc[w][k];                             // LDS broadcast
            a0 += p * v4.x; a1 += p * v4.y; a2 += p * v4.z; a3 += p * v4.w;
        }
        float4 o; o.x = a0; o.y = a1; o.z = a2; o.w = a3;
        *(float4*)&OUT[((size_t)b * NQ + q0 + w) * NDV + lane * 4] = o;
    }
}

extern "C" void kernel_launch(void* const* d_in, const int* in_sizes, int n_in,
                              void* d_out, int out_size, void* d_ws, size_t ws_size,
                              hipStream_t stream) {
    const float* queries = (const float*)d_in[0];  // [16,128,256] f32
    const float* keys    = (const float*)d_in[1];  // [16,512,256] f32
    const float* values  = (const float*)d_in[2];  // [16,512,256] f32
    const int*   vlen    = (const int*)d_in[3];    // [16] int32
    const float* Wq      = (const float*)d_in[4];  // [256,128] f32
    const float* Wk      = (const float*)d_in[5];  // [256,128] f32
    const float* wv      = (const float*)d_in[6];  // [128] f32
    float* out           = (float*)d_out;          // [16,128,256] f32

    float* qp = (float*)d_ws;                      // 16*128*128 f32 = 1MB
    float* kp = qp + (size_t)NB * NQ * NH;         // 16*512*128 f32 = 4MB

    proj_kernel<NQ><<<NB * NQ / 16, 256, 0, stream>>>(queries, Wq, qp);
    proj_kernel<NK><<<NB * NK / 16, 256, 0, stream>>>(keys, Wk, kp);
    attn_fused_kernel<<<NB * 32, 256, 0, stream>>>(qp, kp, wv, vlen, values, out);
}

// Round 14
// 146.019 us; speedup vs baseline: 1.3558x; 1.3558x over previous
//
#include <hip/hip_runtime.h>
#include <hip/hip_bf16.h>

#define NB 16
#define NQ 128
#define NK 512
#define DIN 256   // QS == KS == 256
#define NH 128
#define NDV 256

#define CSC 2.8853900817779268f   // 2*log2(e): tanh(x) = 1 - 2/(1 + 2^(CSC*x))

// Merged projection kernel. Blocks 0..127: Q-proj (writes QP[b][q][h], scaled
// by CSC). Blocks 128..639: K-proj (writes KPT[b][h][k] TRANSPOSED, scaled).
// Per block: 16 rows of X staged in LDS (16KB); W staged in 4 chunks of
// 64d x 128h (32KB). Thread (h=tid&127, rg=tid>>7) accumulates 8 rows.
__global__ __launch_bounds__(256) void proj_both_kernel(
    const float* __restrict__ Q, const float* __restrict__ K,
    const float* __restrict__ Wq, const float* __restrict__ Wk,
    float* __restrict__ QP, float* __restrict__ KPT)
{
    __shared__ float Xl[16 * DIN];   // 16KB
    __shared__ float Wl[64 * NH];    // 32KB  (d-major chunk; reads are 2-way = free)
    const int tid = threadIdx.x;
    int blk = blockIdx.x;
    const float *X, *W;
    int b, r0, isq;
    if (blk < 128) { isq = 1; b = blk >> 3; r0 = (blk & 7) * 16;
                     X = Q + ((size_t)b * NQ + r0) * DIN; W = Wq; }
    else { blk -= 128; isq = 0; b = blk >> 5; r0 = (blk & 31) * 16;
           X = K + ((size_t)b * NK + r0) * DIN; W = Wk; }

    {   // stage X tile: 4096 floats, coalesced float4
        const float4* Xg = (const float4*)X;
        float4* Xs = (float4*)Xl;
        #pragma unroll
        for (int i = 0; i < 4; ++i) Xs[tid + 256 * i] = Xg[tid + 256 * i];
    }

    const int h  = tid & 127;
    const int rg = tid >> 7;          // rows rg*8 .. rg*8+7
    float acc[8];
    #pragma unroll
    for (int r = 0; r < 8; ++r) acc[r] = 0.f;

    for (int dc = 0; dc < 4; ++dc) {
        __syncthreads();              // Xl ready (dc=0) / Wl reuse safe (dc>0)
        {   // stage W chunk [64d][128h]: 8192 floats coalesced
            const float4* Wg = (const float4*)(W + dc * 64 * NH);
            float4* Ws = (float4*)Wl;
            #pragma unroll
            for (int i = 0; i < 8; ++i) Ws[tid + 256 * i] = Wg[tid + 256 * i];
        }
        __syncthreads();
        #pragma unroll 4
        for (int d = 0; d < 64; d += 4) {
            float w0 = Wl[(d + 0) * NH + h];   // lanes consecutive h: 2-way, free
            float w1 = Wl[(d + 1) * NH + h];
            float w2 = Wl[(d + 2) * NH + h];
            float w3 = Wl[(d + 3) * NH + h];
            #pragma unroll
            for (int r = 0; r < 8; ++r) {
                float4 x = *(const float4*)&Xl[(rg * 8 + r) * DIN + dc * 64 + d];
                acc[r] += x.x * w0 + x.y * w1 + x.z * w2 + x.w * w3;
            }
        }
    }
    if (isq) {
        float* Pp = QP + ((size_t)(b * NQ + r0 + rg * 8)) * NH + h;
        #pragma unroll
        for (int r = 0; r < 8; ++r) Pp[(size_t)r * NH] = acc[r] * CSC;
    } else {
        float* Pp = KPT + ((size_t)b * NH + h) * NK + r0 + rg * 8;
        float4 o0, o1;
        o0.x = acc[0]*CSC; o0.y = acc[1]*CSC; o0.z = acc[2]*CSC; o0.w = acc[3]*CSC;
        o1.x = acc[4]*CSC; o1.y = acc[5]*CSC; o1.z = acc[6]*CSC; o1.w = acc[7]*CSC;
        *(float4*)Pp = o0; *(float4*)(Pp + 4) = o1;
    }
}

// Fused scores + masked softmax + attn@V.  Block = (b, 4 q rows), 256 thr = 4
// waves, grid 512. Scores: thread owns keys {tid, tid+256} x 4 rows = 8
// independent accumulators; KPT reads coalesced (lane-consecutive k); NO LDS
// staging, NO barriers in the hot loop. Softmax per-wave. Out: wave w covers
// all 4 rows for k-quarter w (V[b] read exactly once per block), LDS reduce.
__global__ __launch_bounds__(256) void attn_fused_kernel(
    const float* __restrict__ QP, const float* __restrict__ KPT,
    const float* __restrict__ wv, const int* __restrict__ vlen,
    const float* __restrict__ V, float* __restrict__ OUT)
{
    __shared__ float qcl[4 * NH];          // 2KB   CSC-scaled q-proj
    __shared__ float wvl[NH];              // 0.5KB -2*wv
    __shared__ float sc[4][NK];            // 8KB   scores -> attn
    __shared__ float part[4][4][NDV];      // 16KB  [wave][row][d] partials
    const int tid = threadIdx.x;
    const int b  = blockIdx.x >> 5;
    const int q0 = (blockIdx.x & 31) * 4;

    {
        const float* qg = QP + ((size_t)b * NQ + q0) * NH;
        qcl[tid] = qg[tid];
        qcl[tid + 256] = qg[tid + 256];
        if (tid < NH) wvl[tid] = -2.0f * wv[tid];
    }
    __syncthreads();

    int vl = vlen[b];
    vl = vl < 1 ? 1 : (vl > NK ? NK : vl);

    // ---- scores: score(r,k) = sum_h wvl[h] / (1 + 2^(qcl[r][h] + kptc[h][k]))
    // (equals true score minus sum(wv): softmax-invariant shift)
    {
        const int k1 = tid, k2 = tid + 256;
        const float* kb = KPT + (size_t)b * NH * NK;
        float a[8];
        #pragma unroll
        for (int i = 0; i < 8; ++i) a[i] = 0.f;
        #pragma unroll 4
        for (int h = 0; h < NH; ++h) {
            float kv1 = kb[(size_t)h * NK + k1];   // coalesced 256B/wave
            float kv2 = kb[(size_t)h * NK + k2];
            float wq  = wvl[h];                    // broadcast
            #pragma unroll
            for (int r = 0; r < 4; ++r) {
                float qv = qcl[r * NH + h];        // broadcast
                float t1 = __builtin_amdgcn_exp2f(qv + kv1);
                float t2 = __builtin_amdgcn_exp2f(qv + kv2);
                a[r]     += wq * __builtin_amdgcn_rcpf(t1 + 1.0f);
                a[r + 4] += wq * __builtin_amdgcn_rcpf(t2 + 1.0f);
            }
        }
        const bool v1 = (k1 < vl), v2 = (k2 < vl);
        #pragma unroll
        for (int r = 0; r < 4; ++r) {
            sc[r][k1] = v1 ? a[r]     : -1e6f;
            sc[r][k2] = v2 ? a[r + 4] : -1e6f;
        }
    }
    __syncthreads();

    // ---- masked softmax: wave w owns row w
    const int w = tid >> 6, lane = tid & 63;
    {
        float vals[8];
        float m = -3.0e38f;
        #pragma unroll
        for (int i = 0; i < 8; ++i) { vals[i] = sc[w][lane + 64 * i]; m = fmaxf(m, vals[i]); }
        #pragma unroll
        for (int off = 32; off; off >>= 1) m = fmaxf(m, __shfl_xor(m, off, 64));
        float s = 0.f;
        #pragma unroll
        for (int i = 0; i < 8; ++i) {
            vals[i] = __builtin_amdgcn_exp2f((vals[i] - m) * 1.4426950408889634f);
            s += vals[i];
        }
        #pragma unroll
        for (int off = 32; off; off >>= 1) s += __shfl_xor(s, off, 64);
        const float invs = 1.0f / s;   // s >= 1
        #pragma unroll
        for (int i = 0; i < 8; ++i) sc[w][lane + 64 * i] = vals[i] * invs;
    }
    __syncthreads();

    // ---- out: wave w handles ALL 4 rows for k in [w*128, (w+1)*128)
    // (V[b] read exactly once per block), then LDS partial reduction.
    {
        float4 o[4];
        #pragma unroll
        for (int r = 0; r < 4; ++r) { o[r].x = 0.f; o[r].y = 0.f; o[r].z = 0.f; o[r].w = 0.f; }
        const float* vb = V + (size_t)b * NK * NDV + lane * 4;
        const int kbase = w * 128;
        #pragma unroll 4
        for (int kk = 0; kk < 128; ++kk) {
            const int k = kbase + kk;
            float4 v4 = *(const float4*)(vb + (size_t)k * NDV);   // 1KB/wave coalesced
            float p0 = sc[0][k], p1 = sc[1][k], p2 = sc[2][k], p3 = sc[3][k];
            o[0].x += p0 * v4.x; o[0].y += p0 * v4.y; o[0].z += p0 * v4.z; o[0].w += p0 * v4.w;
            o[1].x += p1 * v4.x; o[1].y += p1 * v4.y; o[1].z += p1 * v4.z; o[1].w += p1 * v4.w;
            o[2].x += p2 * v4.x; o[2].y += p2 * v4.y; o[2].z += p2 * v4.z; o[2].w += p2 * v4.w;
            o[3].x += p3 * v4.x; o[3].y += p3 * v4.y; o[3].z += p3 * v4.z; o[3].w += p3 * v4.w;
        }
        #pragma unroll
        for (int r = 0; r < 4; ++r)
            *(float4*)&part[w][r][lane * 4] = o[r];
    }
    __syncthreads();
    {
        const int r = tid >> 6, d4 = tid & 63;
        float4 p0 = *(const float4*)&part[0][r][d4 * 4];
        float4 p1 = *(const float4*)&part[1][r][d4 * 4];
        float4 p2 = *(const float4*)&part[2][r][d4 * 4];
        float4 p3 = *(const float4*)&part[3][r][d4 * 4];
        float4 s;
        s.x = (p0.x + p1.x) + (p2.x + p3.x);
        s.y = (p0.y + p1.y) + (p2.y + p3.y);
        s.z = (p0.z + p1.z) + (p2.z + p3.z);
        s.w = (p0.w + p1.w) + (p2.w + p3.w);
        *(float4*)&OUT[((size_t)b * NQ + q0 + r) * NDV + d4 * 4] = s;   // coalesced
    }
}

extern "C" void kernel_launch(void* const* d_in, const int* in_sizes, int n_in,
                              void* d_out, int out_size, void* d_ws, size_t ws_size,
                              hipStream_t stream) {
    const float* queries = (const float*)d_in[0];  // [16,128,256] f32
    const float* keys    = (const float*)d_in[1];  // [16,512,256] f32
    const float* values  = (const float*)d_in[2];  // [16,512,256] f32
    const int*   vlen    = (const int*)d_in[3];    // [16] int32
    const float* Wq      = (const float*)d_in[4];  // [256,128] f32
    const float* Wk      = (const float*)d_in[5];  // [256,128] f32
    const float* wv      = (const float*)d_in[6];  // [128] f32
    float* out           = (float*)d_out;          // [16,128,256] f32

    float* qp  = (float*)d_ws;                     // QP  [16][128][128] = 1MB (CSC-scaled)
    float* kpt = qp + (size_t)NB * NQ * NH;        // KPT [16][128][512] = 4MB (CSC-scaled, transposed)

    proj_both_kernel<<<128 + 512, 256, 0, stream>>>(queries, keys, Wq, Wk, qp, kpt);
    attn_fused_kernel<<<NB * 32, 256, 0, stream>>>(qp, kpt, wv, vlen, values, out);
}